// Round 9
// baseline (1150.896 us; speedup 1.0000x reference)
//
#include <hip/hip_runtime.h>
#include <hip/hip_bf16.h>

#define N_NODES 50000
#define N_EDGES 800000
#define D_IN    16
#define D_HID   64
#define D_OUT   16

typedef __hip_bfloat16 bf16;
typedef _Float16 f16;
typedef _Float16 f16x8 __attribute__((ext_vector_type(8)));
typedef float    f32x4 __attribute__((ext_vector_type(4)));
// may_alias pointer element types for LDS reinterpret access
typedef _Float16 f16x8a __attribute__((ext_vector_type(8), may_alias));
typedef unsigned u32a   __attribute__((may_alias));

__device__ __forceinline__ float b2f(bf16 v) { return __bfloat162float(v); }
__device__ __forceinline__ int clampn(int v) {
    return v < 0 ? 0 : (v >= N_NODES ? N_NODES - 1 : v);
}
// dual-dtype scalar read (round-6 evidence: inputs are f32; probe kept as insurance)
__device__ __forceinline__ float rdf(const void* p, long i, int isbf) {
    return isbf ? b2f(((const bf16*)p)[i]) : ((const float*)p)[i];
}

__global__ void k_detect(const unsigned short* __restrict__ xw,
                         const int* __restrict__ ei, int* __restrict__ flags)
{
    if (threadIdx.x == 0) {
        int inband = 0;
        for (int j = 0; j < 256; j++) {
            unsigned short w = xw[2 * j];
            int e = (w >> 7) & 0xFF;
            if ((w & 0x7FFF) == 0 || (e >= 100 && e <= 140)) inband++;
        }
        flags[0] = (inband >= 192) ? 1 : 0;
        int z = 1;
        for (int j = 1; j < 128; j += 2) z &= (ei[j] == 0) ? 1 : 0;
        flags[1] = z;
    }
}

__global__ __launch_bounds__(256) void k_zero4(float4* __restrict__ p, int n4)
{
    int i = blockIdx.x * 256 + threadIdx.x;
    if (i < n4) p[i] = (float4){0.f, 0.f, 0.f, 0.f};
}

__global__ __launch_bounds__(256) void k_lin_in(const int* __restrict__ flags,
                                                const void* __restrict__ x,
                                                const void* __restrict__ w,
                                                const void* __restrict__ b,
                                                float* __restrict__ h)
{
    int idx = blockIdx.x * 256 + threadIdx.x;
    if (idx >= N_NODES * D_HID) return;
    const int isbf = flags[0];
    int n = idx >> 6, c = idx & 63;
    float acc = rdf(b, c, isbf);
#pragma unroll
    for (int i = 0; i < D_IN; i++)
        acc += rdf(x, (long)n * D_IN + i, isbf) * rdf(w, (long)i * D_HID + c, isbf);
    h[idx] = acc;
}

// ---------------------------------------------------------------------------
// MFMA edge MLP. One wave = 16 edges through all 3 layers.
// mfma_f32_16x16x32_f16:  A[m=lane&15][k=quad*8+j]  B[k=quad*8+j][n=lane&15]
//                         D col=lane&15, row=quad*4+reg   (m89/m120 verified)
// ROUND-9 CHANGE (occupancy experiment): y-buffer now ALIASES the xin region
// (wave-private DS ops are program-ordered; A-frags hoisted before y-stores,
// so the in-place overwrite is safe). LDS 65,024 -> 53,760 B => 3 blocks/CU
// (was 2). Weight LDS must stay resident: VGPR_Count=116 shows the compiler
// re-reads B-frags from LDS instead of pinning 128 VGPRs - destroying that
// region would force ~180 VGPR and cost a wave/SIMD.
// ---------------------------------------------------------------------------
#define XIN_ST 136   // halves; 272B rows: 16B-aligned, <=2-way banks
#define Y_ST    88   // halves; 176B rows (within the xin region)
#define W0_ST  136
#define W1_ST   72   // 144B rows: 16B-aligned, 2-way

__global__ __launch_bounds__(256, 3) void k_edge_mfma(
    const int* __restrict__ flags, const int* __restrict__ eidx,
    const float* __restrict__ hin, float* __restrict__ hout,
    const void* __restrict__ gw0, const void* __restrict__ gb0,
    const void* __restrict__ gw1, const void* __restrict__ gb1,
    const void* __restrict__ gw2, const void* __restrict__ gb2, int kblk)
{
    __shared__ f16 w0T[64 * W0_ST];          // 17408 B
    __shared__ f16 w1T[64 * W1_ST];          //  9216 B
    __shared__ f16 w2T[64 * W1_ST];          //  9216 B
    __shared__ f16 xin_s[4][16 * XIN_ST];    // 17408 B (xin AND y live here)
    __shared__ int sidx_s[4][32];            //   512 B
    // total 53,760 B -> 3 blocks/CU

    const int tid  = threadIdx.x;
    const int isbf = flags[0];
    const int is64 = flags[1];

    // ---- stage transposed weights (w?T[n][k]) in f16 ----
    const long wb0 = (long)kblk * 2 * D_HID * D_HID;
    for (int i = tid; i < 2 * D_HID * D_HID; i += 256) {
        int n = i >> 7, k = i & 127;
        w0T[n * W0_ST + k] = (f16)rdf(gw0, wb0 + (long)k * 64 + n, isbf);
    }
    const long wb1 = (long)kblk * D_HID * D_HID;
    for (int i = tid; i < D_HID * D_HID; i += 256) {
        int n = i >> 6, k = i & 63;
        w1T[n * W1_ST + k] = (f16)rdf(gw1, wb1 + (long)k * 64 + n, isbf);
        w2T[n * W1_ST + k] = (f16)rdf(gw2, wb1 + (long)k * 64 + n, isbf);
    }
    __syncthreads();

    const int wv = tid >> 6, ln = tid & 63;
    const int lm = ln & 15, quad = ln >> 4;

    // ---- weight B-frags (compiler keeps LDS-resident, re-reads per use) ----
    f16x8 bw0[4][4], bw1[2][4], bw2[2][4];
#pragma unroll
    for (int c = 0; c < 4; c++)
#pragma unroll
        for (int t = 0; t < 4; t++)
            bw0[c][t] = *(const f16x8a*)&w0T[(t * 16 + lm) * W0_ST + c * 32 + quad * 8];
#pragma unroll
    for (int c = 0; c < 2; c++)
#pragma unroll
        for (int t = 0; t < 4; t++) {
            bw1[c][t] = *(const f16x8a*)&w1T[(t * 16 + lm) * W1_ST + c * 32 + quad * 8];
            bw2[c][t] = *(const f16x8a*)&w2T[(t * 16 + lm) * W1_ST + c * 32 + quad * 8];
        }
    float bias0[4], bias1[4], bias2[4];
#pragma unroll
    for (int t = 0; t < 4; t++) {
        bias0[t] = rdf(gb0, (long)kblk * 64 + t * 16 + lm, isbf);
        bias1[t] = rdf(gb1, (long)kblk * 64 + t * 16 + lm, isbf);
        bias2[t] = rdf(gb2, (long)kblk * 64 + t * 16 + lm, isbf);
    }

    const int  strd  = is64 ? 2 : 1;
    const long dbase = is64 ? (long)(2 * N_EDGES) : (long)N_EDGES;

    f16* xin  = xin_s[wv];
    f16* yb   = xin_s[wv];   // ALIAS: y overwrites xin after A-frags consumed
    int* sidx = sidx_s[wv];
    const int half = ln >> 5, lc = ln & 31;

    const int gwave = blockIdx.x * 4 + wv;
    const int nwave = gridDim.x * 4;

    for (int g = gwave; g < N_EDGES / 16; g += nwave) {
        const int eb = g * 16;
        if (ln < 32) {
            int e = ln & 15;
            long ii = (ln < 16) ? (long)(eb + e) * strd
                                : dbase + (long)(eb + e) * strd;
            sidx[ln] = clampn(eidx[ii]);
        }
        // ---- gather cat(h_src, h_dst) -> xin f16 [16][128] ----
        float2 gv[16];
#pragma unroll
        for (int e = 0; e < 16; e++) {
            int idx = sidx[half * 16 + e];
            gv[e] = *(const float2*)&hin[(long)idx * 64 + lc * 2];
        }
#pragma unroll
        for (int e = 0; e < 16; e++) {
            union { unsigned u; f16 h[2]; } p;
            p.h[0] = (f16)gv[e].x; p.h[1] = (f16)gv[e].y;
            *(u32a*)&xin[e * XIN_ST + lc * 2 + half * 64] = p.u;
        }

        // ---- layer 0: [16x128]@[128x64] + bias, relu ----
        f16x8 a0[4];
#pragma unroll
        for (int c = 0; c < 4; c++)   // hoisted: consume xin before y-store
            a0[c] = *(const f16x8a*)&xin[lm * XIN_ST + c * 32 + quad * 8];
        f32x4 acc[4];
#pragma unroll
        for (int t = 0; t < 4; t++)
            acc[t] = (f32x4){bias0[t], bias0[t], bias0[t], bias0[t]};
#pragma unroll
        for (int c = 0; c < 4; c++)
#pragma unroll
            for (int t = 0; t < 4; t++)
                acc[t] = __builtin_amdgcn_mfma_f32_16x16x32_f16(a0[c], bw0[c][t], acc[t], 0, 0, 0);
#pragma unroll
        for (int t = 0; t < 4; t++)
#pragma unroll
            for (int r = 0; r < 4; r++)
                yb[(quad * 4 + r) * Y_ST + t * 16 + lm] = (f16)fmaxf(acc[t][r], 0.f);

        // ---- layer 1: [16x64]@[64x64] + bias, relu ----
        f16x8 a1[2];
#pragma unroll
        for (int c = 0; c < 2; c++)
            a1[c] = *(const f16x8a*)&yb[lm * Y_ST + c * 32 + quad * 8];
#pragma unroll
        for (int t = 0; t < 4; t++)
            acc[t] = (f32x4){bias1[t], bias1[t], bias1[t], bias1[t]};
#pragma unroll
        for (int c = 0; c < 2; c++)
#pragma unroll
            for (int t = 0; t < 4; t++)
                acc[t] = __builtin_amdgcn_mfma_f32_16x16x32_f16(a1[c], bw1[c][t], acc[t], 0, 0, 0);
#pragma unroll
        for (int t = 0; t < 4; t++)
#pragma unroll
            for (int r = 0; r < 4; r++)
                yb[(quad * 4 + r) * Y_ST + t * 16 + lm] = (f16)fmaxf(acc[t][r], 0.f);

        // ---- layer 2: [16x64]@[64x64] + bias (no relu) ----
        f16x8 a2[2];
#pragma unroll
        for (int c = 0; c < 2; c++)
            a2[c] = *(const f16x8a*)&yb[lm * Y_ST + c * 32 + quad * 8];
#pragma unroll
        for (int t = 0; t < 4; t++)
            acc[t] = (f32x4){bias2[t], bias2[t], bias2[t], bias2[t]};
#pragma unroll
        for (int c = 0; c < 2; c++)
#pragma unroll
            for (int t = 0; t < 4; t++)
                acc[t] = __builtin_amdgcn_mfma_f32_16x16x32_f16(a2[c], bw2[c][t], acc[t], 0, 0, 0);

        // ---- scatter-add (C-layout: row=edge=quad*4+r, col=t*16+lm) ----
        int drow[4];
#pragma unroll
        for (int r = 0; r < 4; r++) drow[r] = sidx[16 + quad * 4 + r];
#pragma unroll
        for (int t = 0; t < 4; t++)
#pragma unroll
            for (int r = 0; r < 4; r++)
                atomicAdd(&hout[(long)drow[r] * 64 + t * 16 + lm], acc[t][r]);
    }
}

__global__ __launch_bounds__(256) void k_lin_out(const int* __restrict__ flags,
                                                 const float* __restrict__ h,
                                                 const void* __restrict__ w,
                                                 const void* __restrict__ b,
                                                 float* __restrict__ out)
{
    int idx = blockIdx.x * 256 + threadIdx.x;
    if (idx >= N_NODES * D_OUT) return;
    const int isbf = flags[0];
    int n = idx >> 4, c = idx & 15;
    float acc = rdf(b, c, isbf);
    const float* hr = h + (long)n * D_HID;
#pragma unroll
    for (int i = 0; i < D_HID; i++) acc += hr[i] * rdf(w, (long)i * D_OUT + c, isbf);
    out[idx] = acc;
}

extern "C" void kernel_launch(void* const* d_in, const int* in_sizes, int n_in,
                              void* d_out, int out_size, void* d_ws, size_t ws_size,
                              hipStream_t stream)
{
    const void* x    = d_in[0];
    // d_in[1] = lframes: unused by the reference
    const int*  ei   = (const int*)d_in[2];
    const void* liw  = d_in[3];
    const void* lib  = d_in[4];
    const void* w0   = d_in[5];
    const void* b0   = d_in[6];
    const void* w1   = d_in[7];
    const void* b1   = d_in[8];
    const void* w2   = d_in[9];
    const void* b2   = d_in[10];
    const void* low  = d_in[11];
    const void* lob  = d_in[12];
    float* out = (float*)d_out;

    // ws layout: [flags: 256B][hA: 12.8MB][hB: 12.8MB]
    int*   flags = (int*)d_ws;
    float* hA = (float*)d_ws + 64;
    float* hB = hA + (size_t)N_NODES * D_HID;

    const int HN = N_NODES * D_HID;
    const int gH = (HN + 255) / 256;

    k_detect<<<1, 64, 0, stream>>>((const unsigned short*)x, ei, flags);
    k_lin_in<<<gH, 256, 0, stream>>>(flags, x, liw, lib, hA);

    float* cur = hA;
    float* nxt = hB;
    for (int k = 0; k < 4; k++) {
        k_zero4<<<(HN / 4 + 255) / 256, 256, 0, stream>>>((float4*)nxt, HN / 4);
        // 768 blocks = 3 blocks/CU (LDS 53,760 x 3 = 161,280 <= 163,840)
        k_edge_mfma<<<768, 256, 0, stream>>>(flags, ei, cur, nxt,
                                             w0, b0, w1, b1, w2, b2, k);
        float* t = cur; cur = nxt; nxt = t;
    }

    k_lin_out<<<(N_NODES * D_OUT + 255) / 256, 256, 0, stream>>>(flags, cur, low, lob, out);
}

// Round 10
// 923.043 us; speedup vs baseline: 1.2468x; 1.2468x over previous
//
#include <hip/hip_runtime.h>
#include <hip/hip_bf16.h>

#define N_NODES 50000
#define N_EDGES 800000
#define D_IN    16
#define D_HID   64
#define D_OUT   16

typedef __hip_bfloat16 bf16;
typedef _Float16 f16;
typedef _Float16 f16x8 __attribute__((ext_vector_type(8)));
typedef float    f32x4 __attribute__((ext_vector_type(4)));
typedef _Float16 f16x8a __attribute__((ext_vector_type(8), may_alias));
typedef unsigned u32a   __attribute__((may_alias));

__device__ __forceinline__ float b2f(bf16 v) { return __bfloat162float(v); }
__device__ __forceinline__ int clampn(int v) {
    return v < 0 ? 0 : (v >= N_NODES ? N_NODES - 1 : v);
}
__device__ __forceinline__ float rdf(const void* p, long i, int isbf) {
    return isbf ? b2f(((const bf16*)p)[i]) : ((const float*)p)[i];
}
__device__ __forceinline__ f16x8 relu8(f16x8 v) {
#pragma unroll
    for (int j = 0; j < 8; j++) v[j] = v[j] > (f16)0 ? v[j] : (f16)0;
    return v;
}

__global__ void k_detect(const unsigned short* __restrict__ xw,
                         const int* __restrict__ ei, int* __restrict__ flags)
{
    if (threadIdx.x == 0) {
        int inband = 0;
        for (int j = 0; j < 256; j++) {
            unsigned short w = xw[2 * j];
            int e = (w >> 7) & 0xFF;
            if ((w & 0x7FFF) == 0 || (e >= 100 && e <= 140)) inband++;
        }
        flags[0] = (inband >= 192) ? 1 : 0;
        int z = 1;
        for (int j = 1; j < 128; j += 2) z &= (ei[j] == 0) ? 1 : 0;
        flags[1] = z;
    }
}

__global__ __launch_bounds__(256) void k_zero4(float4* __restrict__ p, int n4)
{
    int i = blockIdx.x * 256 + threadIdx.x;
    if (i < n4) p[i] = (float4){0.f, 0.f, 0.f, 0.f};
}

__global__ __launch_bounds__(256) void k_lin_in(const int* __restrict__ flags,
                                                const void* __restrict__ x,
                                                const void* __restrict__ w,
                                                const void* __restrict__ b,
                                                float* __restrict__ h)
{
    int idx = blockIdx.x * 256 + threadIdx.x;
    if (idx >= N_NODES * D_HID) return;
    const int isbf = flags[0];
    int n = idx >> 6, c = idx & 63;
    float acc = rdf(b, c, isbf);
#pragma unroll
    for (int i = 0; i < D_IN; i++)
        acc += rdf(x, (long)n * D_IN + i, isbf) * rdf(w, (long)i * D_HID + c, isbf);
    h[idx] = acc;
}

// ---------------------------------------------------------------------------
// Node projection: Psrc = H @ W0[0:64,:],  Pdst = H @ W0[64:128,:] + b0,
// both stored f16 [N_NODES][64]. Splits layer-0 over the concat halves so the
// edge kernel gathers 128B f16 rows (half the bytes) and skips layer-0 MFMA.
// One wave = 16 nodes (sequential rows, fully coalesced). 3125 waves.
// ---------------------------------------------------------------------------
#define W0P_ST 136   // halves
#define HP_ST   72

__global__ __launch_bounds__(256) void k_proj(
    const int* __restrict__ flags, const float* __restrict__ hin,
    const void* __restrict__ gw0, const void* __restrict__ gb0,
    f16* __restrict__ psrc, f16* __restrict__ pdst, int kblk)
{
    __shared__ f16 w0T[64 * W0P_ST];        // 17408 B  [n][k], k=0..127
    __shared__ f16 hL_s[4][16 * HP_ST];     //  9216 B

    const int tid  = threadIdx.x;
    const int isbf = flags[0];

    const long wb0 = (long)kblk * 2 * D_HID * D_HID;
    for (int i = tid; i < 2 * D_HID * D_HID; i += 256) {
        int n = i >> 7, k = i & 127;
        w0T[n * W0P_ST + k] = (f16)rdf(gw0, wb0 + (long)k * 64 + n, isbf);
    }
    __syncthreads();

    const int wv = tid >> 6, ln = tid & 63;
    const int lm = ln & 15, quad = ln >> 4;
    f16* hL = hL_s[wv];

    const int g = blockIdx.x * 4 + wv;
    if (g >= N_NODES / 16) return;
    const int n0 = g * 16;

    // stage 16 node rows f32->f16 (coalesced)
#pragma unroll
    for (int i = 0; i < 16; i++) {
        int idx = i * 64 + ln;
        hL[(idx >> 6) * HP_ST + (idx & 63)] = (f16)hin[(long)n0 * 64 + idx];
    }

    f16x8 a[2];
#pragma unroll
    for (int c = 0; c < 2; c++)
        a[c] = *(const f16x8a*)&hL[lm * HP_ST + c * 32 + quad * 8];

    f32x4 accS[4], accD[4];
#pragma unroll
    for (int t = 0; t < 4; t++) {
        float bd = rdf(gb0, (long)kblk * 64 + t * 16 + lm, isbf);
        accS[t] = (f32x4){0.f, 0.f, 0.f, 0.f};
        accD[t] = (f32x4){bd, bd, bd, bd};
    }
#pragma unroll
    for (int c = 0; c < 2; c++)
#pragma unroll
        for (int t = 0; t < 4; t++) {
            f16x8 bs = *(const f16x8a*)&w0T[(t * 16 + lm) * W0P_ST + c * 32 + quad * 8];
            f16x8 bd = *(const f16x8a*)&w0T[(t * 16 + lm) * W0P_ST + 64 + c * 32 + quad * 8];
            accS[t] = __builtin_amdgcn_mfma_f32_16x16x32_f16(a[c], bs, accS[t], 0, 0, 0);
            accD[t] = __builtin_amdgcn_mfma_f32_16x16x32_f16(a[c], bd, accD[t], 0, 0, 0);
        }
    // C layout: row=quad*4+r (node), col=t*16+lm (channel)
#pragma unroll
    for (int t = 0; t < 4; t++)
#pragma unroll
        for (int r = 0; r < 4; r++) {
            long o = (long)(n0 + quad * 4 + r) * 64 + t * 16 + lm;
            psrc[o] = (f16)accS[t][r];
            pdst[o] = (f16)accD[t][r];
        }
}

// ---------------------------------------------------------------------------
// Edge kernel: layer-0 = relu(Psrc[s] + Pdst[d]) (f16 adds, 2x128B gather);
// layers 1-2 via MFMA (m89/m120-verified layouts); scatter atomicAdd.
// y in-place alias with hoisted A-frags (round-9-verified). 512 blocks:
// round-9 lesson — concurrency above 2 blocks/CU thrashes L2 reuse window.
// LDS 28,160 B.
// ---------------------------------------------------------------------------
#define Y_ST  72
#define W1_ST 72

__global__ __launch_bounds__(256, 2) void k_edge_mfma(
    const int* __restrict__ flags, const int* __restrict__ eidx,
    const f16* __restrict__ psrc, const f16* __restrict__ pdst,
    float* __restrict__ hout,
    const void* __restrict__ gw1, const void* __restrict__ gb1,
    const void* __restrict__ gw2, const void* __restrict__ gb2, int kblk)
{
    __shared__ f16 w1T[64 * W1_ST];          // 9216 B
    __shared__ f16 w2T[64 * W1_ST];          // 9216 B
    __shared__ f16 y_s[4][16 * Y_ST];        // 9216 B
    __shared__ int sidx_s[4][32];            //  512 B

    const int tid  = threadIdx.x;
    const int isbf = flags[0];
    const int is64 = flags[1];

    const long wb1 = (long)kblk * D_HID * D_HID;
    for (int i = tid; i < D_HID * D_HID; i += 256) {
        int n = i >> 6, k = i & 63;
        w1T[n * W1_ST + k] = (f16)rdf(gw1, wb1 + (long)k * 64 + n, isbf);
        w2T[n * W1_ST + k] = (f16)rdf(gw2, wb1 + (long)k * 64 + n, isbf);
    }
    __syncthreads();

    const int wv = tid >> 6, ln = tid & 63;
    const int lm = ln & 15, quad = ln >> 4;

    f16x8 bw1[2][4], bw2[2][4];
#pragma unroll
    for (int c = 0; c < 2; c++)
#pragma unroll
        for (int t = 0; t < 4; t++) {
            bw1[c][t] = *(const f16x8a*)&w1T[(t * 16 + lm) * W1_ST + c * 32 + quad * 8];
            bw2[c][t] = *(const f16x8a*)&w2T[(t * 16 + lm) * W1_ST + c * 32 + quad * 8];
        }
    float bias1[4], bias2[4];
#pragma unroll
    for (int t = 0; t < 4; t++) {
        bias1[t] = rdf(gb1, (long)kblk * 64 + t * 16 + lm, isbf);
        bias2[t] = rdf(gb2, (long)kblk * 64 + t * 16 + lm, isbf);
    }

    const int  strd  = is64 ? 2 : 1;
    const long dbase = is64 ? (long)(2 * N_EDGES) : (long)N_EDGES;

    f16* yb   = y_s[wv];
    int* sidx = sidx_s[wv];
    const int sub = ln & 7, eh = ln >> 3;   // gather role: 8 lanes/edge-row

    const int gwave = blockIdx.x * 4 + wv;
    const int nwave = gridDim.x * 4;

    for (int g = gwave; g < N_EDGES / 16; g += nwave) {
        const int eb = g * 16;
        if (ln < 32) {
            int e = ln & 15;
            long ii = (ln < 16) ? (long)(eb + e) * strd
                                : dbase + (long)(eb + e) * strd;
            sidx[ln] = clampn(eidx[ii]);
        }
        // ---- layer 0: y[e] = relu(Psrc[s_e] + Pdst[d_e])  (2 passes x 8 edges)
#pragma unroll
        for (int p = 0; p < 2; p++) {
            int e = p * 8 + eh;
            int s = sidx[e], d = sidx[16 + e];
            f16x8 ps = *(const f16x8a*)&psrc[(long)s * 64 + sub * 8];
            f16x8 pd = *(const f16x8a*)&pdst[(long)d * 64 + sub * 8];
            *(f16x8a*)&yb[e * Y_ST + sub * 8] = relu8(ps + pd);
        }

        // ---- layer 1: [16x64]@[64x64] + b1, relu (in-place, A hoisted) ----
        f16x8 a1[2];
#pragma unroll
        for (int c = 0; c < 2; c++)
            a1[c] = *(const f16x8a*)&yb[lm * Y_ST + c * 32 + quad * 8];
        f32x4 acc[4];
#pragma unroll
        for (int t = 0; t < 4; t++)
            acc[t] = (f32x4){bias1[t], bias1[t], bias1[t], bias1[t]};
#pragma unroll
        for (int c = 0; c < 2; c++)
#pragma unroll
            for (int t = 0; t < 4; t++)
                acc[t] = __builtin_amdgcn_mfma_f32_16x16x32_f16(a1[c], bw1[c][t], acc[t], 0, 0, 0);
#pragma unroll
        for (int t = 0; t < 4; t++)
#pragma unroll
            for (int r = 0; r < 4; r++)
                yb[(quad * 4 + r) * Y_ST + t * 16 + lm] = (f16)fmaxf(acc[t][r], 0.f);

        // ---- layer 2: [16x64]@[64x64] + b2 ----
        f16x8 a2[2];
#pragma unroll
        for (int c = 0; c < 2; c++)
            a2[c] = *(const f16x8a*)&yb[lm * Y_ST + c * 32 + quad * 8];
#pragma unroll
        for (int t = 0; t < 4; t++)
            acc[t] = (f32x4){bias2[t], bias2[t], bias2[t], bias2[t]};
#pragma unroll
        for (int c = 0; c < 2; c++)
#pragma unroll
            for (int t = 0; t < 4; t++)
                acc[t] = __builtin_amdgcn_mfma_f32_16x16x32_f16(a2[c], bw2[c][t], acc[t], 0, 0, 0);

        // ---- scatter-add (C: row=edge=quad*4+r, col=t*16+lm) ----
        int drow[4];
#pragma unroll
        for (int r = 0; r < 4; r++) drow[r] = sidx[16 + quad * 4 + r];
#pragma unroll
        for (int t = 0; t < 4; t++)
#pragma unroll
            for (int r = 0; r < 4; r++)
                atomicAdd(&hout[(long)drow[r] * 64 + t * 16 + lm], acc[t][r]);
    }
}

__global__ __launch_bounds__(256) void k_lin_out(const int* __restrict__ flags,
                                                 const float* __restrict__ h,
                                                 const void* __restrict__ w,
                                                 const void* __restrict__ b,
                                                 float* __restrict__ out)
{
    int idx = blockIdx.x * 256 + threadIdx.x;
    if (idx >= N_NODES * D_OUT) return;
    const int isbf = flags[0];
    int n = idx >> 4, c = idx & 15;
    float acc = rdf(b, c, isbf);
    const float* hr = h + (long)n * D_HID;
#pragma unroll
    for (int i = 0; i < D_HID; i++) acc += hr[i] * rdf(w, (long)i * D_OUT + c, isbf);
    out[idx] = acc;
}

extern "C" void kernel_launch(void* const* d_in, const int* in_sizes, int n_in,
                              void* d_out, int out_size, void* d_ws, size_t ws_size,
                              hipStream_t stream)
{
    const void* x    = d_in[0];
    const int*  ei   = (const int*)d_in[2];
    const void* liw  = d_in[3];
    const void* lib  = d_in[4];
    const void* w0   = d_in[5];
    const void* b0   = d_in[6];
    const void* w1   = d_in[7];
    const void* b1   = d_in[8];
    const void* w2   = d_in[9];
    const void* b2   = d_in[10];
    const void* low  = d_in[11];
    const void* lob  = d_in[12];
    float* out = (float*)d_out;

    // ws: [flags 256B][hA 12.8M][hB 12.8M][Psrc 6.4M][Pdst 6.4M] = 38.7MB
    int*   flags = (int*)d_ws;
    float* hA = (float*)d_ws + 64;
    float* hB = hA + (size_t)N_NODES * D_HID;
    f16*   Psrc = (f16*)(hB + (size_t)N_NODES * D_HID);
    f16*   Pdst = Psrc + (size_t)N_NODES * D_HID;

    const int HN = N_NODES * D_HID;
    const int gH = (HN + 255) / 256;

    k_detect<<<1, 64, 0, stream>>>((const unsigned short*)x, ei, flags);
    k_lin_in<<<gH, 256, 0, stream>>>(flags, x, liw, lib, hA);

    float* cur = hA;
    float* nxt = hB;
    for (int k = 0; k < 4; k++) {
        k_proj<<<(N_NODES / 16 + 3) / 4, 256, 0, stream>>>(flags, cur, w0, b0, Psrc, Pdst, k);
        k_zero4<<<(HN / 4 + 255) / 256, 256, 0, stream>>>((float4*)nxt, HN / 4);
        // 512 blocks = 2 blocks/CU: round-9 lesson, L2 reuse-window caps concurrency
        k_edge_mfma<<<512, 256, 0, stream>>>(flags, ei, Psrc, Pdst, nxt,
                                             w1, b1, w2, b2, k);
        float* t = cur; cur = nxt; nxt = t;
    }

    k_lin_out<<<(N_NODES * D_OUT + 255) / 256, 256, 0, stream>>>(flags, cur, low, lob, out);
}

// Round 12
// 819.486 us; speedup vs baseline: 1.4044x; 1.1264x over previous
//
#include <hip/hip_runtime.h>
#include <hip/hip_bf16.h>

#define N_NODES 50000
#define N_EDGES 800000
#define D_IN    16
#define D_HID   64
#define D_OUT   16

typedef __hip_bfloat16 bf16;
typedef _Float16 f16;
typedef _Float16 f16x8 __attribute__((ext_vector_type(8)));
typedef float    f32x4 __attribute__((ext_vector_type(4)));
typedef _Float16 f16x8a __attribute__((ext_vector_type(8), may_alias));

__device__ __forceinline__ float b2f(bf16 v) { return __bfloat162float(v); }
__device__ __forceinline__ int clampn(int v) {
    return v < 0 ? 0 : (v >= N_NODES ? N_NODES - 1 : v);
}
__device__ __forceinline__ float rdf(const void* p, long i, int isbf) {
    return isbf ? b2f(((const bf16*)p)[i]) : ((const float*)p)[i];
}
__device__ __forceinline__ f16x8 relu8(f16x8 v) {
#pragma unroll
    for (int j = 0; j < 8; j++) v[j] = v[j] > (f16)0 ? v[j] : (f16)0;
    return v;
}

__global__ void k_detect(const unsigned short* __restrict__ xw,
                         const int* __restrict__ ei, int* __restrict__ flags)
{
    if (threadIdx.x == 0) {
        int inband = 0;
        for (int j = 0; j < 256; j++) {
            unsigned short w = xw[2 * j];
            int e = (w >> 7) & 0xFF;
            if ((w & 0x7FFF) == 0 || (e >= 100 && e <= 140)) inband++;
        }
        flags[0] = (inband >= 192) ? 1 : 0;
        int z = 1;
        for (int j = 1; j < 128; j += 2) z &= (ei[j] == 0) ? 1 : 0;
        flags[1] = z;
    }
}

__global__ __launch_bounds__(256) void k_zero_i(int* __restrict__ p, int n)
{
    int i = blockIdx.x * 256 + threadIdx.x;
    if (i < n) p[i] = 0;
}

// ---- counting sort of edges by dst (once per launch; reused by 4 blocks) ----
__global__ __launch_bounds__(256) void k_hist(const int* __restrict__ flags,
                                              const int* __restrict__ eidx,
                                              int* __restrict__ hist)
{
    int e = blockIdx.x * 256 + threadIdx.x;
    if (e >= N_EDGES) return;
    const int strd = flags[1] ? 2 : 1;
    const long dbase = flags[1] ? (long)(2 * N_EDGES) : (long)N_EDGES;
    int d = clampn(eidx[dbase + (long)e * strd]);
    atomicAdd(&hist[d], 1);
}

// single-block exclusive scan: 1024 threads x strip of 49 bins
__global__ __launch_bounds__(1024) void k_scan(const int* __restrict__ hist,
                                               int* __restrict__ off,
                                               int* __restrict__ cursor)
{
    __shared__ int part[1024];
    const int t = threadIdx.x;
    const int lo = t * 49;
    const int hi = min(lo + 49, N_NODES);
    int s = 0;
    for (int i = lo; i < hi; i++) s += hist[i];
    part[t] = s;
    __syncthreads();
    for (int d = 1; d < 1024; d <<= 1) {
        int v = (t >= d) ? part[t - d] : 0;
        __syncthreads();
        part[t] += v;
        __syncthreads();
    }
    int run = (t == 0) ? 0 : part[t - 1];
    for (int i = lo; i < hi; i++) {
        off[i] = run; cursor[i] = run; run += hist[i];
    }
    if (t == 1023) off[N_NODES] = part[1023];
}

__global__ __launch_bounds__(256) void k_scatter(const int* __restrict__ flags,
                                                 const int* __restrict__ eidx,
                                                 int* __restrict__ cursor,
                                                 int* __restrict__ eorder)
{
    int e = blockIdx.x * 256 + threadIdx.x;
    if (e >= N_EDGES) return;
    const int strd = flags[1] ? 2 : 1;
    const long dbase = flags[1] ? (long)(2 * N_EDGES) : (long)N_EDGES;
    int d = clampn(eidx[dbase + (long)e * strd]);
    int pos = atomicAdd(&cursor[d], 1);
    eorder[pos] = e;
}

__global__ __launch_bounds__(256) void k_lin_in(const int* __restrict__ flags,
                                                const void* __restrict__ x,
                                                const void* __restrict__ w,
                                                const void* __restrict__ b,
                                                float* __restrict__ h)
{
    int idx = blockIdx.x * 256 + threadIdx.x;
    if (idx >= N_NODES * D_HID) return;
    const int isbf = flags[0];
    int n = idx >> 6, c = idx & 63;
    float acc = rdf(b, c, isbf);
#pragma unroll
    for (int i = 0; i < D_IN; i++)
        acc += rdf(x, (long)n * D_IN + i, isbf) * rdf(w, (long)i * D_HID + c, isbf);
    h[idx] = acc;
}

// ---------------------------------------------------------------------------
// Node projection (round-10 verified): Psrc = H@W0[0:64], Pdst = H@W0[64:]+b0,
// f16 [N][64]. One wave = 16 nodes, coalesced.
// ---------------------------------------------------------------------------
#define W0P_ST 136
#define HP_ST   72

__global__ __launch_bounds__(256) void k_proj(
    const int* __restrict__ flags, const float* __restrict__ hin,
    const void* __restrict__ gw0, const void* __restrict__ gb0,
    f16* __restrict__ psrc, f16* __restrict__ pdst, int kblk)
{
    __shared__ f16 w0T[64 * W0P_ST];
    __shared__ f16 hL_s[4][16 * HP_ST];

    const int tid  = threadIdx.x;
    const int isbf = flags[0];

    const long wb0 = (long)kblk * 2 * D_HID * D_HID;
    for (int i = tid; i < 2 * D_HID * D_HID; i += 256) {
        int n = i >> 7, k = i & 127;
        w0T[n * W0P_ST + k] = (f16)rdf(gw0, wb0 + (long)k * 64 + n, isbf);
    }
    __syncthreads();

    const int wv = tid >> 6, ln = tid & 63;
    const int lm = ln & 15, quad = ln >> 4;
    f16* hL = hL_s[wv];

    const int g = blockIdx.x * 4 + wv;
    if (g >= N_NODES / 16) return;
    const int n0 = g * 16;

#pragma unroll
    for (int i = 0; i < 16; i++) {
        int idx = i * 64 + ln;
        hL[(idx >> 6) * HP_ST + (idx & 63)] = (f16)hin[(long)n0 * 64 + idx];
    }

    f16x8 a[2];
#pragma unroll
    for (int c = 0; c < 2; c++)
        a[c] = *(const f16x8a*)&hL[lm * HP_ST + c * 32 + quad * 8];

    f32x4 accS[4], accD[4];
#pragma unroll
    for (int t = 0; t < 4; t++) {
        float bd = rdf(gb0, (long)kblk * 64 + t * 16 + lm, isbf);
        accS[t] = (f32x4){0.f, 0.f, 0.f, 0.f};
        accD[t] = (f32x4){bd, bd, bd, bd};
    }
#pragma unroll
    for (int c = 0; c < 2; c++)
#pragma unroll
        for (int t = 0; t < 4; t++) {
            f16x8 bs = *(const f16x8a*)&w0T[(t * 16 + lm) * W0P_ST + c * 32 + quad * 8];
            f16x8 bd = *(const f16x8a*)&w0T[(t * 16 + lm) * W0P_ST + 64 + c * 32 + quad * 8];
            accS[t] = __builtin_amdgcn_mfma_f32_16x16x32_f16(a[c], bs, accS[t], 0, 0, 0);
            accD[t] = __builtin_amdgcn_mfma_f32_16x16x32_f16(a[c], bd, accD[t], 0, 0, 0);
        }
#pragma unroll
    for (int t = 0; t < 4; t++)
#pragma unroll
        for (int r = 0; r < 4; r++) {
            long o = (long)(n0 + quad * 4 + r) * 64 + t * 16 + lm;
            psrc[o] = (f16)accS[t][r];
            pdst[o] = (f16)accD[t][r];
        }
}

// ---------------------------------------------------------------------------
// Dst-owned aggregation: one wave = one node. Edges (sorted by dst) in
// 16-edge MFMA tiles; layer-0 = relu(Psrc[s]+Pdst[n]); layers 1-2 MFMA
// (m89/m120-verified); padded rows masked post-layer-2; segment sum in
// registers (cross-quad shfl_xor); PLAIN coalesced stores — zero atomics.
// Writes h IN PLACE (reads only Psrc/Pdst) — no ping-pong buffer needed.
// ---------------------------------------------------------------------------
#define Y_ST  72
#define W1_ST 72

__global__ __launch_bounds__(256) void k_edge_agg(
    const int* __restrict__ flags, const int* __restrict__ eidx,
    const int* __restrict__ eorder, const int* __restrict__ off,
    const int* __restrict__ deg,
    const f16* __restrict__ psrc, const f16* __restrict__ pdst,
    float* __restrict__ hout,
    const void* __restrict__ gw1, const void* __restrict__ gb1,
    const void* __restrict__ gw2, const void* __restrict__ gb2, int kblk)
{
    __shared__ f16 w1T[64 * W1_ST];          // 9216 B
    __shared__ f16 w2T[64 * W1_ST];          // 9216 B
    __shared__ f16 y_s[4][16 * Y_ST];        // 9216 B
    __shared__ int sedge_s[4][16];           //  256 B

    const int tid  = threadIdx.x;
    const int isbf = flags[0];
    const int strd = flags[1] ? 2 : 1;

    const long wb1 = (long)kblk * D_HID * D_HID;
    for (int i = tid; i < D_HID * D_HID; i += 256) {
        int n = i >> 6, k = i & 63;
        w1T[n * W1_ST + k] = (f16)rdf(gw1, wb1 + (long)k * 64 + n, isbf);
        w2T[n * W1_ST + k] = (f16)rdf(gw2, wb1 + (long)k * 64 + n, isbf);
    }
    __syncthreads();

    const int wv = tid >> 6, ln = tid & 63;
    const int lm = ln & 15, quad = ln >> 4;

    f16x8 bw1[2][4], bw2[2][4];
#pragma unroll
    for (int c = 0; c < 2; c++)
#pragma unroll
        for (int t = 0; t < 4; t++) {
            bw1[c][t] = *(const f16x8a*)&w1T[(t * 16 + lm) * W1_ST + c * 32 + quad * 8];
            bw2[c][t] = *(const f16x8a*)&w2T[(t * 16 + lm) * W1_ST + c * 32 + quad * 8];
        }
    float bias1[4], bias2[4];
#pragma unroll
    for (int t = 0; t < 4; t++) {
        bias1[t] = rdf(gb1, (long)kblk * 64 + t * 16 + lm, isbf);
        bias2[t] = rdf(gb2, (long)kblk * 64 + t * 16 + lm, isbf);
    }

    f16* yb    = y_s[wv];
    int* sedge = sedge_s[wv];
    const int sub = ln & 7, eh = ln >> 3;

    const int gwave = blockIdx.x * 4 + wv;
    const int nwave = gridDim.x * 4;

    for (int n = gwave; n < N_NODES; n += nwave) {
        const int o0 = off[n];
        const int dg = deg[n];

        // Pdst row for this node (shared by all its edges)
        f16x8 pd8 = *(const f16x8a*)&pdst[(long)n * 64 + sub * 8];

        float accn[4] = {0.f, 0.f, 0.f, 0.f};

        for (int tb = 0; tb < dg; tb += 16) {
            const int valid = min(16, dg - tb);
            if (ln < 16) {
                int i = (ln < valid) ? ln : 0;
                int eid = eorder[o0 + tb + i];
                sedge[ln] = clampn(eidx[(long)eid * strd]);
            }
            // layer 0: y[e] = relu(Psrc[s_e] + Pdst[n])
#pragma unroll
            for (int p = 0; p < 2; p++) {
                int e = p * 8 + eh;
                int s = sedge[e];
                f16x8 ps = *(const f16x8a*)&psrc[(long)s * 64 + sub * 8];
                *(f16x8a*)&yb[e * Y_ST + sub * 8] = relu8(ps + pd8);
            }
            // layer 1
            f16x8 a1[2];
#pragma unroll
            for (int c = 0; c < 2; c++)
                a1[c] = *(const f16x8a*)&yb[lm * Y_ST + c * 32 + quad * 8];
            f32x4 acc[4];
#pragma unroll
            for (int t = 0; t < 4; t++)
                acc[t] = (f32x4){bias1[t], bias1[t], bias1[t], bias1[t]};
#pragma unroll
            for (int c = 0; c < 2; c++)
#pragma unroll
                for (int t = 0; t < 4; t++)
                    acc[t] = __builtin_amdgcn_mfma_f32_16x16x32_f16(a1[c], bw1[c][t], acc[t], 0, 0, 0);
#pragma unroll
            for (int t = 0; t < 4; t++)
#pragma unroll
                for (int r = 0; r < 4; r++)
                    yb[(quad * 4 + r) * Y_ST + t * 16 + lm] = (f16)fmaxf(acc[t][r], 0.f);
            // layer 2
            f16x8 a2[2];
#pragma unroll
            for (int c = 0; c < 2; c++)
                a2[c] = *(const f16x8a*)&yb[lm * Y_ST + c * 32 + quad * 8];
#pragma unroll
            for (int t = 0; t < 4; t++)
                acc[t] = (f32x4){bias2[t], bias2[t], bias2[t], bias2[t]};
#pragma unroll
            for (int c = 0; c < 2; c++)
#pragma unroll
                for (int t = 0; t < 4; t++)
                    acc[t] = __builtin_amdgcn_mfma_f32_16x16x32_f16(a2[c], bw2[c][t], acc[t], 0, 0, 0);
            // mask padded rows (row = quad*4+r) and accumulate segment sum
#pragma unroll
            for (int t = 0; t < 4; t++)
#pragma unroll
                for (int r = 0; r < 4; r++)
                    if (quad * 4 + r < valid) accn[t] += acc[t][r];
        }

        // reduce over the 4 quads (lanes lm, lm+16, lm+32, lm+48)
#pragma unroll
        for (int t = 0; t < 4; t++) {
            float v = accn[t];
            v += __shfl_xor(v, 16, 64);
            v += __shfl_xor(v, 32, 64);
            if (quad == 0) hout[(long)n * 64 + t * 16 + lm] = v;
        }
    }
}

__global__ __launch_bounds__(256) void k_lin_out(const int* __restrict__ flags,
                                                 const float* __restrict__ h,
                                                 const void* __restrict__ w,
                                                 const void* __restrict__ b,
                                                 float* __restrict__ out)
{
    int idx = blockIdx.x * 256 + threadIdx.x;
    if (idx >= N_NODES * D_OUT) return;
    const int isbf = flags[0];
    int n = idx >> 4, c = idx & 15;
    float acc = rdf(b, c, isbf);
    const float* hr = h + (long)n * D_HID;
#pragma unroll
    for (int i = 0; i < D_HID; i++) acc += hr[i] * rdf(w, (long)i * D_OUT + c, isbf);
    out[idx] = acc;
}

extern "C" void kernel_launch(void* const* d_in, const int* in_sizes, int n_in,
                              void* d_out, int out_size, void* d_ws, size_t ws_size,
                              hipStream_t stream)
{
    const void* x    = d_in[0];
    const int*  ei   = (const int*)d_in[2];
    const void* liw  = d_in[3];
    const void* lib  = d_in[4];
    const void* w0   = d_in[5];
    const void* b0   = d_in[6];
    const void* w1   = d_in[7];
    const void* b1   = d_in[8];
    const void* w2   = d_in[9];
    const void* b2   = d_in[10];
    const void* low  = d_in[11];
    const void* lob  = d_in[12];
    float* out = (float*)d_out;

    // ws: flags(256B) | hA 12.8M | Psrc 6.4M | Pdst 6.4M
    //     | hist 0.2M | off 0.2M | cursor 0.2M | eorder 3.2M  (~29.5 MB,
    //     under the 38.7 MB footprint proven in round 10)
    char* wp = (char*)d_ws;
    int*   flags  = (int*)wp;                 wp += 256;
    float* hA     = (float*)wp;               wp += (size_t)N_NODES * D_HID * 4;
    f16*   Psrc   = (f16*)wp;                 wp += (size_t)N_NODES * D_HID * 2;
    f16*   Pdst   = (f16*)wp;                 wp += (size_t)N_NODES * D_HID * 2;
    int*   hist   = (int*)wp;                 wp += (size_t)N_NODES * 4;
    int*   off    = (int*)wp;                 wp += ((size_t)N_NODES + 64) * 4;
    int*   cursor = (int*)wp;                 wp += (size_t)N_NODES * 4;
    int*   eorder = (int*)wp;

    const int HN = N_NODES * D_HID;
    const int gH = (HN + 255) / 256;
    const int gE = (N_EDGES + 255) / 256;

    k_detect<<<1, 64, 0, stream>>>((const unsigned short*)x, ei, flags);

    // counting sort by dst (edge_index constant across the 4 graph blocks)
    k_zero_i<<<(N_NODES + 255) / 256, 256, 0, stream>>>(hist, N_NODES);
    k_hist<<<gE, 256, 0, stream>>>(flags, ei, hist);
    k_scan<<<1, 1024, 0, stream>>>(hist, off, cursor);
    k_scatter<<<gE, 256, 0, stream>>>(flags, ei, cursor, eorder);

    k_lin_in<<<gH, 256, 0, stream>>>(flags, x, liw, lib, hA);

    for (int k = 0; k < 4; k++) {
        k_proj<<<(N_NODES / 16 + 3) / 4, 256, 0, stream>>>(flags, hA, w0, b0, Psrc, Pdst, k);
        // in-place: k_edge_agg reads only Psrc/Pdst, writes every node of hA
        k_edge_agg<<<1024, 256, 0, stream>>>(flags, ei, eorder, off, hist,
                                             Psrc, Pdst, hA, w1, b1, w2, b2, k);
    }

    k_lin_out<<<(N_NODES * D_OUT + 255) / 256, 256, 0, stream>>>(flags, hA, low, lob, out);
}

// Round 13
// 735.395 us; speedup vs baseline: 1.5650x; 1.1143x over previous
//
#include <hip/hip_runtime.h>
#include <hip/hip_bf16.h>

#define N_NODES 50000
#define N_EDGES 800000
#define D_IN    16
#define D_HID   64
#define D_OUT   16
#define NCHUNK  ((N_NODES + 255) / 256)   // 196 scan chunks

typedef __hip_bfloat16 bf16;
typedef _Float16 f16;
typedef _Float16 f16x8 __attribute__((ext_vector_type(8)));
typedef float    f32x4 __attribute__((ext_vector_type(4)));
typedef _Float16 f16x8a __attribute__((ext_vector_type(8), may_alias));

__device__ __forceinline__ float b2f(bf16 v) { return __bfloat162float(v); }
__device__ __forceinline__ int clampn(int v) {
    return v < 0 ? 0 : (v >= N_NODES ? N_NODES - 1 : v);
}
__device__ __forceinline__ float rdf(const void* p, long i, int isbf) {
    return isbf ? b2f(((const bf16*)p)[i]) : ((const float*)p)[i];
}
__device__ __forceinline__ f16x8 relu8(f16x8 v) {
#pragma unroll
    for (int j = 0; j < 8; j++) v[j] = v[j] > (f16)0 ? v[j] : (f16)0;
    return v;
}

__global__ void k_detect(const unsigned short* __restrict__ xw,
                         const int* __restrict__ ei, int* __restrict__ flags)
{
    if (threadIdx.x == 0) {
        int inband = 0;
        for (int j = 0; j < 256; j++) {
            unsigned short w = xw[2 * j];
            int e = (w >> 7) & 0xFF;
            if ((w & 0x7FFF) == 0 || (e >= 100 && e <= 140)) inband++;
        }
        flags[0] = (inband >= 192) ? 1 : 0;
        int z = 1;
        for (int j = 1; j < 128; j += 2) z &= (ei[j] == 0) ? 1 : 0;
        flags[1] = z;
    }
}

__global__ __launch_bounds__(256) void k_zero_i(int* __restrict__ p, int n)
{
    int i = blockIdx.x * 256 + threadIdx.x;
    if (i < n) p[i] = 0;
}

// ---- counting sort of edges by dst (once per launch; reused by 4 blocks) ----
__global__ __launch_bounds__(256) void k_hist(const int* __restrict__ flags,
                                              const int* __restrict__ eidx,
                                              int* __restrict__ hist)
{
    int e = blockIdx.x * 256 + threadIdx.x;
    if (e >= N_EDGES) return;
    const int strd = flags[1] ? 2 : 1;
    const long dbase = flags[1] ? (long)(2 * N_EDGES) : (long)N_EDGES;
    int d = clampn(eidx[dbase + (long)e * strd]);
    atomicAdd(&hist[d], 1);
}

// ---- parallel exclusive scan over 50000 bins (3 small kernels) ----
__global__ __launch_bounds__(256) void k_scan1(const int* __restrict__ hist,
                                               int* __restrict__ bsum)
{
    __shared__ int red[256];
    int i = blockIdx.x * 256 + threadIdx.x;
    red[threadIdx.x] = (i < N_NODES) ? hist[i] : 0;
    __syncthreads();
    for (int d = 128; d > 0; d >>= 1) {
        if (threadIdx.x < d) red[threadIdx.x] += red[threadIdx.x + d];
        __syncthreads();
    }
    if (threadIdx.x == 0) bsum[blockIdx.x] = red[0];
}

__global__ __launch_bounds__(256) void k_scan2(const int* __restrict__ bsum,
                                               int* __restrict__ boff)
{
    __shared__ int s[256];
    const int t = threadIdx.x;
    s[t] = (t < NCHUNK) ? bsum[t] : 0;
    __syncthreads();
    for (int d = 1; d < 256; d <<= 1) {
        int v = (t >= d) ? s[t - d] : 0;
        __syncthreads();
        s[t] += v;
        __syncthreads();
    }
    if (t < NCHUNK) boff[t] = (t == 0) ? 0 : s[t - 1];
}

__global__ __launch_bounds__(256) void k_scan3(const int* __restrict__ hist,
                                               const int* __restrict__ boff,
                                               int* __restrict__ off,
                                               int* __restrict__ cursor)
{
    __shared__ int s[256];
    const int t = threadIdx.x;
    int i = blockIdx.x * 256 + t;
    int v = (i < N_NODES) ? hist[i] : 0;
    s[t] = v;
    __syncthreads();
    for (int d = 1; d < 256; d <<= 1) {
        int u = (t >= d) ? s[t - d] : 0;
        __syncthreads();
        s[t] += u;
        __syncthreads();
    }
    if (i < N_NODES) {
        int ex = boff[blockIdx.x] + s[t] - v;   // exclusive prefix
        off[i] = ex; cursor[i] = ex;
    }
}

// scatter: materialize SRC indices in dst-sorted order (kills one
// indirection level in the edge kernel: ssrc[pos] -> psrc[...])
__global__ __launch_bounds__(256) void k_scatter(const int* __restrict__ flags,
                                                 const int* __restrict__ eidx,
                                                 int* __restrict__ cursor,
                                                 int* __restrict__ ssrc)
{
    int e = blockIdx.x * 256 + threadIdx.x;
    if (e >= N_EDGES) return;
    const int strd = flags[1] ? 2 : 1;
    const long dbase = flags[1] ? (long)(2 * N_EDGES) : (long)N_EDGES;
    int d = clampn(eidx[dbase + (long)e * strd]);
    int s = clampn(eidx[(long)e * strd]);
    int pos = atomicAdd(&cursor[d], 1);
    ssrc[pos] = s;
}

__global__ __launch_bounds__(256) void k_lin_in(const int* __restrict__ flags,
                                                const void* __restrict__ x,
                                                const void* __restrict__ w,
                                                const void* __restrict__ b,
                                                float* __restrict__ h)
{
    int idx = blockIdx.x * 256 + threadIdx.x;
    if (idx >= N_NODES * D_HID) return;
    const int isbf = flags[0];
    int n = idx >> 6, c = idx & 63;
    float acc = rdf(b, c, isbf);
#pragma unroll
    for (int i = 0; i < D_IN; i++)
        acc += rdf(x, (long)n * D_IN + i, isbf) * rdf(w, (long)i * D_HID + c, isbf);
    h[idx] = acc;
}

// ---------------------------------------------------------------------------
// Node projection (round-10 verified): Psrc = H@W0[0:64], Pdst = H@W0[64:]+b0
// ---------------------------------------------------------------------------
#define W0P_ST 136
#define HP_ST   72

__global__ __launch_bounds__(256) void k_proj(
    const int* __restrict__ flags, const float* __restrict__ hin,
    const void* __restrict__ gw0, const void* __restrict__ gb0,
    f16* __restrict__ psrc, f16* __restrict__ pdst, int kblk)
{
    __shared__ f16 w0T[64 * W0P_ST];
    __shared__ f16 hL_s[4][16 * HP_ST];

    const int tid  = threadIdx.x;
    const int isbf = flags[0];

    const long wb0 = (long)kblk * 2 * D_HID * D_HID;
    for (int i = tid; i < 2 * D_HID * D_HID; i += 256) {
        int n = i >> 7, k = i & 127;
        w0T[n * W0P_ST + k] = (f16)rdf(gw0, wb0 + (long)k * 64 + n, isbf);
    }
    __syncthreads();

    const int wv = tid >> 6, ln = tid & 63;
    const int lm = ln & 15, quad = ln >> 4;
    f16* hL = hL_s[wv];

    const int g = blockIdx.x * 4 + wv;
    if (g >= N_NODES / 16) return;
    const int n0 = g * 16;

#pragma unroll
    for (int i = 0; i < 16; i++) {
        int idx = i * 64 + ln;
        hL[(idx >> 6) * HP_ST + (idx & 63)] = (f16)hin[(long)n0 * 64 + idx];
    }

    f16x8 a[2];
#pragma unroll
    for (int c = 0; c < 2; c++)
        a[c] = *(const f16x8a*)&hL[lm * HP_ST + c * 32 + quad * 8];

    f32x4 accS[4], accD[4];
#pragma unroll
    for (int t = 0; t < 4; t++) {
        float bd = rdf(gb0, (long)kblk * 64 + t * 16 + lm, isbf);
        accS[t] = (f32x4){0.f, 0.f, 0.f, 0.f};
        accD[t] = (f32x4){bd, bd, bd, bd};
    }
#pragma unroll
    for (int c = 0; c < 2; c++)
#pragma unroll
        for (int t = 0; t < 4; t++) {
            f16x8 bs = *(const f16x8a*)&w0T[(t * 16 + lm) * W0P_ST + c * 32 + quad * 8];
            f16x8 bd = *(const f16x8a*)&w0T[(t * 16 + lm) * W0P_ST + 64 + c * 32 + quad * 8];
            accS[t] = __builtin_amdgcn_mfma_f32_16x16x32_f16(a[c], bs, accS[t], 0, 0, 0);
            accD[t] = __builtin_amdgcn_mfma_f32_16x16x32_f16(a[c], bd, accD[t], 0, 0, 0);
        }
#pragma unroll
    for (int t = 0; t < 4; t++)
#pragma unroll
        for (int r = 0; r < 4; r++) {
            long o = (long)(n0 + quad * 4 + r) * 64 + t * 16 + lm;
            psrc[o] = (f16)accS[t][r];
            pdst[o] = (f16)accD[t][r];
        }
}

// ---------------------------------------------------------------------------
// Dst-owned aggregation (zero atomics), round-13 pipelining:
//  - ssrc[] gives src directly (2-deep chain, was 3-deep via eorder)
//  - double-buffered sedge: tile t+1 index loads issue before tile t's
//    gather+compute, hiding the global-load latency
//  - grid 1280 = 5 blocks/CU (LDS residency limit)
// ---------------------------------------------------------------------------
#define Y_ST  72
#define W1_ST 72

__global__ __launch_bounds__(256) void k_edge_agg(
    const int* __restrict__ flags,
    const int* __restrict__ ssrc, const int* __restrict__ off,
    const int* __restrict__ deg,
    const f16* __restrict__ psrc, const f16* __restrict__ pdst,
    float* __restrict__ hout,
    const void* __restrict__ gw1, const void* __restrict__ gb1,
    const void* __restrict__ gw2, const void* __restrict__ gb2, int kblk)
{
    __shared__ f16 w1T[64 * W1_ST];          // 9216 B
    __shared__ f16 w2T[64 * W1_ST];          // 9216 B
    __shared__ f16 y_s[4][16 * Y_ST];        // 9216 B
    __shared__ int sedge_s[4][2][16];        //  512 B   (28,672 B total)

    const int tid  = threadIdx.x;
    const int isbf = flags[0];

    const long wb1 = (long)kblk * D_HID * D_HID;
    for (int i = tid; i < D_HID * D_HID; i += 256) {
        int n = i >> 6, k = i & 63;
        w1T[n * W1_ST + k] = (f16)rdf(gw1, wb1 + (long)k * 64 + n, isbf);
        w2T[n * W1_ST + k] = (f16)rdf(gw2, wb1 + (long)k * 64 + n, isbf);
    }
    __syncthreads();

    const int wv = tid >> 6, ln = tid & 63;
    const int lm = ln & 15, quad = ln >> 4;

    f16x8 bw1[2][4], bw2[2][4];
#pragma unroll
    for (int c = 0; c < 2; c++)
#pragma unroll
        for (int t = 0; t < 4; t++) {
            bw1[c][t] = *(const f16x8a*)&w1T[(t * 16 + lm) * W1_ST + c * 32 + quad * 8];
            bw2[c][t] = *(const f16x8a*)&w2T[(t * 16 + lm) * W1_ST + c * 32 + quad * 8];
        }
    float bias1[4], bias2[4];
#pragma unroll
    for (int t = 0; t < 4; t++) {
        bias1[t] = rdf(gb1, (long)kblk * 64 + t * 16 + lm, isbf);
        bias2[t] = rdf(gb2, (long)kblk * 64 + t * 16 + lm, isbf);
    }

    f16* yb = y_s[wv];
    const int sub = ln & 7, eh = ln >> 3;

    const int gwave = blockIdx.x * 4 + wv;
    const int nwave = gridDim.x * 4;

    for (int n = gwave; n < N_NODES; n += nwave) {
        const int o0 = off[n];
        const int dg = deg[n];
        if (dg == 0) {
#pragma unroll
            for (int t = 0; t < 4; t++)
                if (quad == 0) hout[(long)n * 64 + t * 16 + lm] = 0.f;
            continue;
        }

        f16x8 pd8 = *(const f16x8a*)&pdst[(long)n * 64 + sub * 8];
        float accn[4] = {0.f, 0.f, 0.f, 0.f};

        // prologue: tile-0 indices into buffer 0
        if (ln < 16) {
            int v0 = min(16, dg);
            sedge_s[wv][0][ln] = ssrc[o0 + ((ln < v0) ? ln : 0)];
        }

        int cur = 0;
        for (int tb = 0; tb < dg; tb += 16, cur ^= 1) {
            const int valid = min(16, dg - tb);
            // prefetch next tile's indices into the other buffer
            const int nb = tb + 16;
            if (ln < 16 && nb < dg) {
                int nv = min(16, dg - nb);
                sedge_s[wv][cur ^ 1][ln] = ssrc[o0 + nb + ((ln < nv) ? ln : 0)];
            }
            const int* sedge = sedge_s[wv][cur];

            // layer 0: y[e] = relu(Psrc[s_e] + Pdst[n])
#pragma unroll
            for (int p = 0; p < 2; p++) {
                int e = p * 8 + eh;
                int s = sedge[e];
                f16x8 ps = *(const f16x8a*)&psrc[(long)s * 64 + sub * 8];
                *(f16x8a*)&yb[e * Y_ST + sub * 8] = relu8(ps + pd8);
            }
            // layer 1
            f16x8 a1[2];
#pragma unroll
            for (int c = 0; c < 2; c++)
                a1[c] = *(const f16x8a*)&yb[lm * Y_ST + c * 32 + quad * 8];
            f32x4 acc[4];
#pragma unroll
            for (int t = 0; t < 4; t++)
                acc[t] = (f32x4){bias1[t], bias1[t], bias1[t], bias1[t]};
#pragma unroll
            for (int c = 0; c < 2; c++)
#pragma unroll
                for (int t = 0; t < 4; t++)
                    acc[t] = __builtin_amdgcn_mfma_f32_16x16x32_f16(a1[c], bw1[c][t], acc[t], 0, 0, 0);
#pragma unroll
            for (int t = 0; t < 4; t++)
#pragma unroll
                for (int r = 0; r < 4; r++)
                    yb[(quad * 4 + r) * Y_ST + t * 16 + lm] = (f16)fmaxf(acc[t][r], 0.f);
            // layer 2
            f16x8 a2[2];
#pragma unroll
            for (int c = 0; c < 2; c++)
                a2[c] = *(const f16x8a*)&yb[lm * Y_ST + c * 32 + quad * 8];
#pragma unroll
            for (int t = 0; t < 4; t++)
                acc[t] = (f32x4){bias2[t], bias2[t], bias2[t], bias2[t]};
#pragma unroll
            for (int c = 0; c < 2; c++)
#pragma unroll
                for (int t = 0; t < 4; t++)
                    acc[t] = __builtin_amdgcn_mfma_f32_16x16x32_f16(a2[c], bw2[c][t], acc[t], 0, 0, 0);
            // mask padded rows, accumulate segment sum
#pragma unroll
            for (int t = 0; t < 4; t++)
#pragma unroll
                for (int r = 0; r < 4; r++)
                    if (quad * 4 + r < valid) accn[t] += acc[t][r];
        }

        // reduce over the 4 quads, plain coalesced store
#pragma unroll
        for (int t = 0; t < 4; t++) {
            float v = accn[t];
            v += __shfl_xor(v, 16, 64);
            v += __shfl_xor(v, 32, 64);
            if (quad == 0) hout[(long)n * 64 + t * 16 + lm] = v;
        }
    }
}

__global__ __launch_bounds__(256) void k_lin_out(const int* __restrict__ flags,
                                                 const float* __restrict__ h,
                                                 const void* __restrict__ w,
                                                 const void* __restrict__ b,
                                                 float* __restrict__ out)
{
    int idx = blockIdx.x * 256 + threadIdx.x;
    if (idx >= N_NODES * D_OUT) return;
    const int isbf = flags[0];
    int n = idx >> 4, c = idx & 15;
    float acc = rdf(b, c, isbf);
    const float* hr = h + (long)n * D_HID;
#pragma unroll
    for (int i = 0; i < D_HID; i++) acc += hr[i] * rdf(w, (long)i * D_OUT + c, isbf);
    out[idx] = acc;
}

extern "C" void kernel_launch(void* const* d_in, const int* in_sizes, int n_in,
                              void* d_out, int out_size, void* d_ws, size_t ws_size,
                              hipStream_t stream)
{
    const void* x    = d_in[0];
    const int*  ei   = (const int*)d_in[2];
    const void* liw  = d_in[3];
    const void* lib  = d_in[4];
    const void* w0   = d_in[5];
    const void* b0   = d_in[6];
    const void* w1   = d_in[7];
    const void* b1   = d_in[8];
    const void* w2   = d_in[9];
    const void* b2   = d_in[10];
    const void* low  = d_in[11];
    const void* lob  = d_in[12];
    float* out = (float*)d_out;

    // ws: flags | hA 12.8M | Psrc 6.4M | Pdst 6.4M | hist/off/cursor 0.6M
    //     | bsum/boff 2KB | ssrc 3.2M   (~29.5 MB, under proven 38.7 MB)
    char* wp = (char*)d_ws;
    int*   flags  = (int*)wp;                 wp += 256;
    float* hA     = (float*)wp;               wp += (size_t)N_NODES * D_HID * 4;
    f16*   Psrc   = (f16*)wp;                 wp += (size_t)N_NODES * D_HID * 2;
    f16*   Pdst   = (f16*)wp;                 wp += (size_t)N_NODES * D_HID * 2;
    int*   hist   = (int*)wp;                 wp += (size_t)N_NODES * 4;
    int*   off    = (int*)wp;                 wp += (size_t)N_NODES * 4;
    int*   cursor = (int*)wp;                 wp += (size_t)N_NODES * 4;
    int*   bsum   = (int*)wp;                 wp += 256 * 4;
    int*   boff   = (int*)wp;                 wp += 256 * 4;
    int*   ssrc   = (int*)wp;

    const int HN = N_NODES * D_HID;
    const int gH = (HN + 255) / 256;
    const int gE = (N_EDGES + 255) / 256;

    k_detect<<<1, 64, 0, stream>>>((const unsigned short*)x, ei, flags);

    // counting sort by dst (edge_index constant across the 4 graph blocks)
    k_zero_i<<<(N_NODES + 255) / 256, 256, 0, stream>>>(hist, N_NODES);
    k_hist<<<gE, 256, 0, stream>>>(flags, ei, hist);
    k_scan1<<<NCHUNK, 256, 0, stream>>>(hist, bsum);
    k_scan2<<<1, 256, 0, stream>>>(bsum, boff);
    k_scan3<<<NCHUNK, 256, 0, stream>>>(hist, boff, off, cursor);
    k_scatter<<<gE, 256, 0, stream>>>(flags, ei, cursor, ssrc);

    k_lin_in<<<gH, 256, 0, stream>>>(flags, x, liw, lib, hA);

    for (int k = 0; k < 4; k++) {
        k_proj<<<(N_NODES / 16 + 3) / 4, 256, 0, stream>>>(flags, hA, w0, b0, Psrc, Pdst, k);
        // in-place: k_edge_agg reads only Psrc/Pdst, writes every node of hA
        k_edge_agg<<<1280, 256, 0, stream>>>(flags, ssrc, off, hist,
                                             Psrc, Pdst, hA, w1, b1, w2, b2, k);
    }

    k_lin_out<<<(N_NODES * D_OUT + 255) / 256, 256, 0, stream>>>(flags, hA, low, lob, out);
}

// Round 14
// 625.821 us; speedup vs baseline: 1.8390x; 1.1751x over previous
//
#include <hip/hip_runtime.h>
#include <hip/hip_bf16.h>

#define N_NODES 50000
#define N_EDGES 800000
#define D_IN    16
#define D_HID   64
#define D_OUT   16
#define NCHUNK  ((N_NODES + 255) / 256)   // 196 scan chunks
#define TMAX    100352                    // >= N/16-pad tile bound (50k+50k)

typedef __hip_bfloat16 bf16;
typedef _Float16 f16;
typedef _Float16 f16x8 __attribute__((ext_vector_type(8)));
typedef float    f32x4 __attribute__((ext_vector_type(4)));
typedef _Float16 f16x8a __attribute__((ext_vector_type(8), may_alias));

__device__ __forceinline__ float b2f(bf16 v) { return __bfloat162float(v); }
__device__ __forceinline__ int clampn(int v) {
    return v < 0 ? 0 : (v >= N_NODES ? N_NODES - 1 : v);
}
__device__ __forceinline__ float rdf(const void* p, long i, int isbf) {
    return isbf ? b2f(((const bf16*)p)[i]) : ((const float*)p)[i];
}
__device__ __forceinline__ f16x8 relu8(f16x8 v) {
#pragma unroll
    for (int j = 0; j < 8; j++) v[j] = v[j] > (f16)0 ? v[j] : (f16)0;
    return v;
}

__global__ void k_detect(const unsigned short* __restrict__ xw,
                         const int* __restrict__ ei, int* __restrict__ flags)
{
    if (threadIdx.x == 0) {
        int inband = 0;
        for (int j = 0; j < 256; j++) {
            unsigned short w = xw[2 * j];
            int e = (w >> 7) & 0xFF;
            if ((w & 0x7FFF) == 0 || (e >= 100 && e <= 140)) inband++;
        }
        flags[0] = (inband >= 192) ? 1 : 0;
        int z = 1;
        for (int j = 1; j < 128; j += 2) z &= (ei[j] == 0) ? 1 : 0;
        flags[1] = z;
    }
}

__global__ __launch_bounds__(256) void k_zero_i(int* __restrict__ p, int n)
{
    int i = blockIdx.x * 256 + threadIdx.x;
    if (i < n) p[i] = 0;
}

__global__ __launch_bounds__(256) void k_zero4(float4* __restrict__ p, int n4)
{
    int i = blockIdx.x * 256 + threadIdx.x;
    if (i < n4) p[i] = (float4){0.f, 0.f, 0.f, 0.f};
}

// ---- counting sort of edges by dst + padded tile list (once per launch) ----
__global__ __launch_bounds__(256) void k_hist(const int* __restrict__ flags,
                                              const int* __restrict__ eidx,
                                              int* __restrict__ hist)
{
    int e = blockIdx.x * 256 + threadIdx.x;
    if (e >= N_EDGES) return;
    const int strd = flags[1] ? 2 : 1;
    const long dbase = flags[1] ? (long)(2 * N_EDGES) : (long)N_EDGES;
    int d = clampn(eidx[dbase + (long)e * strd]);
    atomicAdd(&hist[d], 1);
}

// generic 3-stage exclusive scan over N_NODES bins
__global__ __launch_bounds__(256) void k_scan1(const int* __restrict__ in,
                                               int* __restrict__ bsum)
{
    __shared__ int red[256];
    int i = blockIdx.x * 256 + threadIdx.x;
    red[threadIdx.x] = (i < N_NODES) ? in[i] : 0;
    __syncthreads();
    for (int d = 128; d > 0; d >>= 1) {
        if (threadIdx.x < d) red[threadIdx.x] += red[threadIdx.x + d];
        __syncthreads();
    }
    if (threadIdx.x == 0) bsum[blockIdx.x] = red[0];
}

__global__ __launch_bounds__(256) void k_scan2(const int* __restrict__ bsum,
                                               int* __restrict__ boff,
                                               int* __restrict__ total_out)
{
    __shared__ int s[256];
    const int t = threadIdx.x;
    s[t] = (t < NCHUNK) ? bsum[t] : 0;
    __syncthreads();
    for (int d = 1; d < 256; d <<= 1) {
        int v = (t >= d) ? s[t - d] : 0;
        __syncthreads();
        s[t] += v;
        __syncthreads();
    }
    if (t < NCHUNK) boff[t] = (t == 0) ? 0 : s[t - 1];
    if (t == NCHUNK - 1) total_out[0] = s[t];
}

__global__ __launch_bounds__(256) void k_scan3(const int* __restrict__ in,
                                               const int* __restrict__ boff,
                                               int* __restrict__ off,
                                               int* __restrict__ cursor)
{
    __shared__ int s[256];
    const int t = threadIdx.x;
    int i = blockIdx.x * 256 + t;
    int v = (i < N_NODES) ? in[i] : 0;
    s[t] = v;
    __syncthreads();
    for (int d = 1; d < 256; d <<= 1) {
        int u = (t >= d) ? s[t - d] : 0;
        __syncthreads();
        s[t] += u;
        __syncthreads();
    }
    if (i < N_NODES) {
        int ex = boff[blockIdx.x] + s[t] - v;   // exclusive prefix
        off[i] = ex; cursor[i] = ex;
    }
}

// scatter: src indices in dst-sorted order
__global__ __launch_bounds__(256) void k_scatter(const int* __restrict__ flags,
                                                 const int* __restrict__ eidx,
                                                 int* __restrict__ cursor,
                                                 int* __restrict__ ssrc)
{
    int e = blockIdx.x * 256 + threadIdx.x;
    if (e >= N_EDGES) return;
    const int strd = flags[1] ? 2 : 1;
    const long dbase = flags[1] ? (long)(2 * N_EDGES) : (long)N_EDGES;
    int d = clampn(eidx[dbase + (long)e * strd]);
    int s = clampn(eidx[(long)e * strd]);
    int pos = atomicAdd(&cursor[d], 1);
    ssrc[pos] = s;
}

__global__ __launch_bounds__(256) void k_ntile(const int* __restrict__ hist,
                                               int* __restrict__ ntile)
{
    int n = blockIdx.x * 256 + threadIdx.x;
    if (n < N_NODES) ntile[n] = (hist[n] + 15) >> 4;
}

// build padded tile list: ssrc_pad[16t+i] = src idx (last edge replicated),
// tmeta[t] = node | (valid<<20)
__global__ __launch_bounds__(256) void k_fillpad(const int* __restrict__ hist,
                                                 const int* __restrict__ off,
                                                 const int* __restrict__ toff,
                                                 const int* __restrict__ ssrc,
                                                 int* __restrict__ ssrc_pad,
                                                 int* __restrict__ tmeta)
{
    int n = blockIdx.x * 256 + threadIdx.x;
    if (n >= N_NODES) return;
    int dg = hist[n];
    if (dg == 0) return;
    int o0 = off[n], t0 = toff[n], nt = (dg + 15) >> 4;
    for (int j = 0; j < nt; j++) {
        int valid = min(16, dg - 16 * j);
        tmeta[t0 + j] = n | (valid << 20);
        for (int i = 0; i < 16; i++)
            ssrc_pad[(t0 + j) * 16 + i] = ssrc[o0 + min(16 * j + i, dg - 1)];
    }
}

__global__ __launch_bounds__(256) void k_lin_in(const int* __restrict__ flags,
                                                const void* __restrict__ x,
                                                const void* __restrict__ w,
                                                const void* __restrict__ b,
                                                float* __restrict__ h)
{
    int idx = blockIdx.x * 256 + threadIdx.x;
    if (idx >= N_NODES * D_HID) return;
    const int isbf = flags[0];
    int n = idx >> 6, c = idx & 63;
    float acc = rdf(b, c, isbf);
#pragma unroll
    for (int i = 0; i < D_IN; i++)
        acc += rdf(x, (long)n * D_IN + i, isbf) * rdf(w, (long)i * D_HID + c, isbf);
    h[idx] = acc;
}

// ---------------------------------------------------------------------------
// Node projection (round-10 verified): Psrc = H@W0[0:64], Pdst = H@W0[64:]+b0
// ---------------------------------------------------------------------------
#define W0P_ST 136
#define HP_ST   72

__global__ __launch_bounds__(256) void k_proj(
    const int* __restrict__ flags, const float* __restrict__ hin,
    const void* __restrict__ gw0, const void* __restrict__ gb0,
    f16* __restrict__ psrc, f16* __restrict__ pdst, int kblk)
{
    __shared__ f16 w0T[64 * W0P_ST];
    __shared__ f16 hL_s[4][16 * HP_ST];

    const int tid  = threadIdx.x;
    const int isbf = flags[0];

    const long wb0 = (long)kblk * 2 * D_HID * D_HID;
    for (int i = tid; i < 2 * D_HID * D_HID; i += 256) {
        int n = i >> 7, k = i & 127;
        w0T[n * W0P_ST + k] = (f16)rdf(gw0, wb0 + (long)k * 64 + n, isbf);
    }
    __syncthreads();

    const int wv = tid >> 6, ln = tid & 63;
    const int lm = ln & 15, quad = ln >> 4;
    f16* hL = hL_s[wv];

    const int g = blockIdx.x * 4 + wv;
    if (g >= N_NODES / 16) return;
    const int n0 = g * 16;

#pragma unroll
    for (int i = 0; i < 16; i++) {
        int idx = i * 64 + ln;
        hL[(idx >> 6) * HP_ST + (idx & 63)] = (f16)hin[(long)n0 * 64 + idx];
    }

    f16x8 a[2];
#pragma unroll
    for (int c = 0; c < 2; c++)
        a[c] = *(const f16x8a*)&hL[lm * HP_ST + c * 32 + quad * 8];

    f32x4 accS[4], accD[4];
#pragma unroll
    for (int q = 0; q < 4; q++) {
        float bd = rdf(gb0, (long)kblk * 64 + q * 16 + lm, isbf);
        accS[q] = (f32x4){0.f, 0.f, 0.f, 0.f};
        accD[q] = (f32x4){bd, bd, bd, bd};
    }
#pragma unroll
    for (int c = 0; c < 2; c++)
#pragma unroll
        for (int q = 0; q < 4; q++) {
            f16x8 bs = *(const f16x8a*)&w0T[(q * 16 + lm) * W0P_ST + c * 32 + quad * 8];
            f16x8 bd = *(const f16x8a*)&w0T[(q * 16 + lm) * W0P_ST + 64 + c * 32 + quad * 8];
            accS[q] = __builtin_amdgcn_mfma_f32_16x16x32_f16(a[c], bs, accS[q], 0, 0, 0);
            accD[q] = __builtin_amdgcn_mfma_f32_16x16x32_f16(a[c], bd, accD[q], 0, 0, 0);
        }
#pragma unroll
    for (int q = 0; q < 4; q++)
#pragma unroll
        for (int r = 0; r < 4; r++) {
            long o = (long)(n0 + quad * 4 + r) * 64 + q * 16 + lm;
            psrc[o] = (f16)accS[q][r];
            pdst[o] = (f16)accD[q][r];
        }
}

// ---------------------------------------------------------------------------
// Uniform tile-list aggregation with register software pipeline (depth 2):
// iteration tt issues: tmeta/ssrc_pad for tile tt+2, psrc/pdst data for tile
// tt+1 (all into REGISTERS — no LDS round-trip, every consumed value was
// issued a full iteration earlier), computes tile tt, flushes on node change
// (wave-uniform) via atomicAdd into pre-zeroed hout. Waves own contiguous
// equal tile ranges -> perfect balance, no node-boundary serial ramp.
// ---------------------------------------------------------------------------
#define Y_ST  72
#define W1_ST 72

__global__ __launch_bounds__(256) void k_edge_tile(
    const int* __restrict__ flags,
    const int* __restrict__ ssrc_pad, const int* __restrict__ tmeta,
    const int* __restrict__ toff,
    const f16* __restrict__ psrc, const f16* __restrict__ pdst,
    float* __restrict__ hout,
    const void* __restrict__ gw1, const void* __restrict__ gb1,
    const void* __restrict__ gw2, const void* __restrict__ gb2, int kblk)
{
    __shared__ f16 w1T[64 * W1_ST];          // 9216 B
    __shared__ f16 w2T[64 * W1_ST];          // 9216 B
    __shared__ f16 y_s[4][16 * Y_ST];        // 9216 B

    const int tid  = threadIdx.x;
    const int isbf = flags[0];

    const long wb1 = (long)kblk * D_HID * D_HID;
    for (int i = tid; i < D_HID * D_HID; i += 256) {
        int n = i >> 6, k = i & 63;
        w1T[n * W1_ST + k] = (f16)rdf(gw1, wb1 + (long)k * 64 + n, isbf);
        w2T[n * W1_ST + k] = (f16)rdf(gw2, wb1 + (long)k * 64 + n, isbf);
    }
    __syncthreads();

    const int wv = tid >> 6, ln = tid & 63;
    const int lm = ln & 15, quad = ln >> 4;

    f16x8 bw1[2][4], bw2[2][4];
#pragma unroll
    for (int c = 0; c < 2; c++)
#pragma unroll
        for (int q = 0; q < 4; q++) {
            bw1[c][q] = *(const f16x8a*)&w1T[(q * 16 + lm) * W1_ST + c * 32 + quad * 8];
            bw2[c][q] = *(const f16x8a*)&w2T[(q * 16 + lm) * W1_ST + c * 32 + quad * 8];
        }
    float bias1[4], bias2[4];
#pragma unroll
    for (int q = 0; q < 4; q++) {
        bias1[q] = rdf(gb1, (long)kblk * 64 + q * 16 + lm, isbf);
        bias2[q] = rdf(gb2, (long)kblk * 64 + q * 16 + lm, isbf);
    }

    f16* yb = y_s[wv];
    const int sub = ln & 7, eh = ln >> 3;

    const int T  = toff[N_NODES];
    const int W  = gridDim.x * 4;
    const int gw = blockIdx.x * 4 + wv;
    const int t0 = (int)((long)gw * T / W);
    const int t1 = (int)((long)(gw + 1) * T / W);
    if (t0 >= t1) return;

    // ---- pipeline prologue ----
    int tc1 = min(t0 + 1, T - 1);
    int m0 = tmeta[t0], m1 = tmeta[tc1];
    int s1a = ssrc_pad[tc1 * 16 + eh], s1b = ssrc_pad[tc1 * 16 + 8 + eh];
    int s0a = ssrc_pad[t0 * 16 + eh],  s0b = ssrc_pad[t0 * 16 + 8 + eh];
    f16x8 ps0a = *(const f16x8a*)&psrc[(long)s0a * 64 + sub * 8];
    f16x8 ps0b = *(const f16x8a*)&psrc[(long)s0b * 64 + sub * 8];
    f16x8 pd0  = *(const f16x8a*)&pdst[(long)(m0 & 0xFFFFF) * 64 + sub * 8];

    float accn[4] = {0.f, 0.f, 0.f, 0.f};

    for (int tt = t0; tt < t1; tt++) {
        // ---- prefetch (registers only) ----
        const int t2 = min(tt + 2, T - 1);
        int m2  = tmeta[t2];
        int s2a = ssrc_pad[t2 * 16 + eh], s2b = ssrc_pad[t2 * 16 + 8 + eh];
        f16x8 ps1a = *(const f16x8a*)&psrc[(long)s1a * 64 + sub * 8];
        f16x8 ps1b = *(const f16x8a*)&psrc[(long)s1b * 64 + sub * 8];
        f16x8 pd1  = *(const f16x8a*)&pdst[(long)(m1 & 0xFFFFF) * 64 + sub * 8];

        // ---- compute tile tt ----
        const int valid = m0 >> 20;
        *(f16x8a*)&yb[eh * Y_ST + sub * 8]       = relu8(ps0a + pd0);
        *(f16x8a*)&yb[(8 + eh) * Y_ST + sub * 8] = relu8(ps0b + pd0);

        f16x8 a1[2];
#pragma unroll
        for (int c = 0; c < 2; c++)
            a1[c] = *(const f16x8a*)&yb[lm * Y_ST + c * 32 + quad * 8];
        f32x4 acc[4];
#pragma unroll
        for (int q = 0; q < 4; q++)
            acc[q] = (f32x4){bias1[q], bias1[q], bias1[q], bias1[q]};
#pragma unroll
        for (int c = 0; c < 2; c++)
#pragma unroll
            for (int q = 0; q < 4; q++)
                acc[q] = __builtin_amdgcn_mfma_f32_16x16x32_f16(a1[c], bw1[c][q], acc[q], 0, 0, 0);
#pragma unroll
        for (int q = 0; q < 4; q++)
#pragma unroll
            for (int r = 0; r < 4; r++)
                yb[(quad * 4 + r) * Y_ST + q * 16 + lm] = (f16)fmaxf(acc[q][r], 0.f);

        f16x8 a2[2];
#pragma unroll
        for (int c = 0; c < 2; c++)
            a2[c] = *(const f16x8a*)&yb[lm * Y_ST + c * 32 + quad * 8];
#pragma unroll
        for (int q = 0; q < 4; q++)
            acc[q] = (f32x4){bias2[q], bias2[q], bias2[q], bias2[q]};
#pragma unroll
        for (int c = 0; c < 2; c++)
#pragma unroll
            for (int q = 0; q < 4; q++)
                acc[q] = __builtin_amdgcn_mfma_f32_16x16x32_f16(a2[c], bw2[c][q], acc[q], 0, 0, 0);

#pragma unroll
        for (int q = 0; q < 4; q++)
#pragma unroll
            for (int r = 0; r < 4; r++)
                if (quad * 4 + r < valid) accn[q] += acc[q][r];

        // ---- flush on node change (wave-uniform branch) ----
        const int curn  = m0 & 0xFFFFF;
        const int nextn = (tt + 1 < t1) ? (m1 & 0xFFFFF) : -1;
        if (nextn != curn) {
#pragma unroll
            for (int q = 0; q < 4; q++) {
                float v = accn[q];
                v += __shfl_xor(v, 16, 64);
                v += __shfl_xor(v, 32, 64);
                if (quad == 0) atomicAdd(&hout[(long)curn * 64 + q * 16 + lm], v);
                accn[q] = 0.f;
            }
        }

        // ---- rotate pipeline ----
        m0 = m1; m1 = m2;
        s1a = s2a; s1b = s2b;
        ps0a = ps1a; ps0b = ps1b; pd0 = pd1;
    }
}

__global__ __launch_bounds__(256) void k_lin_out(const int* __restrict__ flags,
                                                 const float* __restrict__ h,
                                                 const void* __restrict__ w,
                                                 const void* __restrict__ b,
                                                 float* __restrict__ out)
{
    int idx = blockIdx.x * 256 + threadIdx.x;
    if (idx >= N_NODES * D_OUT) return;
    const int isbf = flags[0];
    int n = idx >> 4, c = idx & 15;
    float acc = rdf(b, c, isbf);
    const float* hr = h + (long)n * D_HID;
#pragma unroll
    for (int i = 0; i < D_HID; i++) acc += hr[i] * rdf(w, (long)i * D_OUT + c, isbf);
    out[idx] = acc;
}

extern "C" void kernel_launch(void* const* d_in, const int* in_sizes, int n_in,
                              void* d_out, int out_size, void* d_ws, size_t ws_size,
                              hipStream_t stream)
{
    const void* x    = d_in[0];
    const int*  ei   = (const int*)d_in[2];
    const void* liw  = d_in[3];
    const void* lib  = d_in[4];
    const void* w0   = d_in[5];
    const void* b0   = d_in[6];
    const void* w1   = d_in[7];
    const void* b1   = d_in[8];
    const void* w2   = d_in[9];
    const void* b2   = d_in[10];
    const void* low  = d_in[11];
    const void* lob  = d_in[12];
    float* out = (float*)d_out;

    // ws (~36.8 MB, under proven 38.7 MB)
    char* wp = (char*)d_ws;
    int*   flags  = (int*)wp;                 wp += 256;
    float* hA     = (float*)wp;               wp += (size_t)N_NODES * D_HID * 4;
    f16*   Psrc   = (f16*)wp;                 wp += (size_t)N_NODES * D_HID * 2;
    f16*   Pdst   = (f16*)wp;                 wp += (size_t)N_NODES * D_HID * 2;
    int*   hist   = (int*)wp;                 wp += (size_t)N_NODES * 4;
    int*   off    = (int*)wp;                 wp += ((size_t)N_NODES + 1) * 4;
    int*   cursor = (int*)wp;                 wp += (size_t)N_NODES * 4;
    int*   ntile  = (int*)wp;                 wp += (size_t)N_NODES * 4;
    int*   toff   = (int*)wp;                 wp += ((size_t)N_NODES + 1) * 4;
    int*   tcur   = (int*)wp;                 wp += (size_t)N_NODES * 4;
    int*   bsum   = (int*)wp;                 wp += 256 * 4;
    int*   boff   = (int*)wp;                 wp += 256 * 4;
    int*   ssrc   = (int*)wp;                 wp += (size_t)N_EDGES * 4;
    int*   tmeta  = (int*)wp;                 wp += (size_t)TMAX * 4;
    int*   spad   = (int*)wp;                 // TMAX*16 ints = 6.4 MB

    const int HN = N_NODES * D_HID;
    const int gH = (HN + 255) / 256;
    const int gE = (N_EDGES + 255) / 256;
    const int gN = (N_NODES + 255) / 256;

    k_detect<<<1, 64, 0, stream>>>((const unsigned short*)x, ei, flags);

    // one-time: dst-sort + padded tile list (reused by all 4 graph blocks)
    k_zero_i<<<gN, 256, 0, stream>>>(hist, N_NODES);
    k_hist<<<gE, 256, 0, stream>>>(flags, ei, hist);
    k_scan1<<<NCHUNK, 256, 0, stream>>>(hist, bsum);
    k_scan2<<<1, 256, 0, stream>>>(bsum, boff, off + N_NODES);
    k_scan3<<<NCHUNK, 256, 0, stream>>>(hist, boff, off, cursor);
    k_scatter<<<gE, 256, 0, stream>>>(flags, ei, cursor, ssrc);
    k_ntile<<<gN, 256, 0, stream>>>(hist, ntile);
    k_scan1<<<NCHUNK, 256, 0, stream>>>(ntile, bsum);
    k_scan2<<<1, 256, 0, stream>>>(bsum, boff, toff + N_NODES);
    k_scan3<<<NCHUNK, 256, 0, stream>>>(ntile, boff, toff, tcur);
    k_fillpad<<<gN, 256, 0, stream>>>(hist, off, toff, ssrc, spad, tmeta);

    k_lin_in<<<gH, 256, 0, stream>>>(flags, x, liw, lib, hA);

    for (int k = 0; k < 4; k++) {
        k_proj<<<(N_NODES / 16 + 3) / 4, 256, 0, stream>>>(flags, hA, w0, b0, Psrc, Pdst, k);
        k_zero4<<<(HN / 4 + 255) / 256, 256, 0, stream>>>((float4*)hA, HN / 4);
        k_edge_tile<<<1024, 256, 0, stream>>>(flags, spad, tmeta, toff,
                                              Psrc, Pdst, hA, w1, b1, w2, b2, k);
    }

    k_lin_out<<<(N_NODES * D_OUT + 255) / 256, 256, 0, stream>>>(flags, hA, low, lob, out);
}